// Round 1
// baseline (9401.268 us; speedup 1.0000x reference)
//
#include <hip/hip_runtime.h>

// WindowAttention fused kernel — Round 0: correct fp32 baseline.
// Structure: Kernel A = per-window fused QKV+attention -> d_out (pre-proj)
//            Kernel B = in-place output projection on d_out
// No d_ws usage (ws_size unknown; avoid 1.85GB qkv materialization).

#define NWIN 4096
#define NW_MASK 1024
#define NH 12
#define DIM 384
#define HD 32
#define HD_P 33          // padded LDS stride: (n*33+k)%32 varies with n -> no bank conflict
#define NT 49            // tokens per window
#define CHUNK 128        // K-chunk for x staging (keeps LDS ~54KB)
#define THREADS_A 384

__global__ __launch_bounds__(THREADS_A)
void win_attn_kernel(const float* __restrict__ x,       // (4096,49,384)
                     const float* __restrict__ mask,    // (1024,49,49)
                     const float* __restrict__ qkv_w,   // (384,1152)
                     const float* __restrict__ qkv_b,   // (1152)
                     const float* __restrict__ rpb,     // (169,12)
                     const int*   __restrict__ rel,     // (49,49)
                     float* __restrict__ y)             // (4096,49,384) pre-proj out
{
    __shared__ float xs[NT * CHUNK];      // 25088 B
    __shared__ float qs[NT * HD_P];       // 6468 B
    __shared__ float ks_[NT * HD_P];      // 6468 B
    __shared__ float vs[NT * HD_P];       // 6468 B
    __shared__ float lg[NT * NT];         // 9604 B   -> total ~54 KB

    const int b = blockIdx.x;
    const int t = threadIdx.x;
    const float* xb = x + (size_t)b * (NT * DIM);
    const float* mrow = mask + (size_t)(b & (NW_MASK - 1)) * (NT * NT);

    // qkv micro-tile mapping: thread owns one output column (p,d) and rows ty+4i
    const int tx = t % 96;           // 96 = 3 parts * 32 dims
    const int ty = t / 96;           // 0..3
    const int p  = tx / 32;          // 0=q 1=k 2=v
    const int d  = tx % 32;

    for (int h = 0; h < NH; ++h) {
        float acc[13];
        #pragma unroll
        for (int i = 0; i < 13; ++i) acc[i] = 0.f;
        const int wcol = p * DIM + h * HD + d;

        for (int c = 0; c < 3; ++c) {
            __syncthreads();   // previous consumers of xs (and prev head's PV) done
            // stage x rows 0..48, cols [c*128, c*128+128) as float4
            for (int i = t; i < NT * (CHUNK / 4); i += THREADS_A) {
                int r = i >> 5;          // / 32 float4s per chunk-row
                int j = i & 31;
                ((float4*)xs)[i] = ((const float4*)xb)[r * 96 + c * 32 + j];
            }
            __syncthreads();
            const float4* xs4 = (const float4*)xs;
            const float* wb = qkv_w + (size_t)(c * CHUNK) * (3 * DIM) + wcol;
            for (int kk4 = 0; kk4 < CHUNK / 4; ++kk4) {
                // 4 w values loaded once, reused across 12-13 rows (register reuse)
                float w0 = wb[(size_t)(kk4 * 4 + 0) * (3 * DIM)];
                float w1 = wb[(size_t)(kk4 * 4 + 1) * (3 * DIM)];
                float w2 = wb[(size_t)(kk4 * 4 + 2) * (3 * DIM)];
                float w3 = wb[(size_t)(kk4 * 4 + 3) * (3 * DIM)];
                #pragma unroll
                for (int i = 0; i < 13; ++i) {
                    int r = ty + 4 * i;
                    if (r < NT) {
                        float4 xv = xs4[r * 32 + kk4];   // broadcast within wave
                        acc[i] += xv.x * w0;
                        acc[i] += xv.y * w1;
                        acc[i] += xv.z * w2;
                        acc[i] += xv.w * w3;
                    }
                }
            }
        }
        float bv = qkv_b[wcol];
        float* dst = (p == 0) ? qs : (p == 1) ? ks_ : vs;
        #pragma unroll
        for (int i = 0; i < 13; ++i) {
            int r = ty + 4 * i;
            if (r < NT) dst[r * HD_P + d] = acc[i] + bv;
        }
        __syncthreads();

        // logits = scale * q.k^T + rel-pos bias + window mask
        for (int idx = t; idx < NT * NT; idx += THREADS_A) {
            int n = idx / NT, m = idx % NT;
            float s = 0.f;
            #pragma unroll
            for (int kk = 0; kk < HD; ++kk)
                s += qs[n * HD_P + kk] * ks_[m * HD_P + kk];
            s = s * 0.17677669529663687f            // 32^-0.5
                + rpb[rel[idx] * NH + h] + mrow[idx];
            lg[idx] = s;
        }
        __syncthreads();

        // softmax per row (49 rows, thread t handles row t)
        if (t < NT) {
            float mx = -1e30f;
            for (int m = 0; m < NT; ++m) mx = fmaxf(mx, lg[t * NT + m]);
            float sum = 0.f;
            for (int m = 0; m < NT; ++m) {
                float e = __expf(lg[t * NT + m] - mx);
                lg[t * NT + m] = e;
                sum += e;
            }
            float inv = 1.f / sum;
            for (int m = 0; m < NT; ++m) lg[t * NT + m] *= inv;
        }
        __syncthreads();

        // out = P @ V, written in (b, n, h*32+d) layout
        for (int idx = t; idx < NT * HD; idx += THREADS_A) {
            int n = idx >> 5, dd = idx & 31;
            float s = 0.f;
            #pragma unroll
            for (int m = 0; m < NT; ++m)
                s += lg[n * NT + m] * vs[m * HD_P + dd];
            y[(size_t)b * (NT * DIM) + n * DIM + h * HD + dd] = s;
        }
        // next head's first __syncthreads() (chunk loop) provides the barrier
    }
}

// In-place projection: each block owns 16 rows; reads them to LDS, then
// overwrites. Row-independent => in-place safe.
#define RPB 16
__global__ __launch_bounds__(384)
void proj_kernel(const float* __restrict__ proj_w,   // (384,384)
                 const float* __restrict__ proj_b,   // (384)
                 float* __restrict__ y)              // (200704,384) in-place
{
    __shared__ float ys[RPB * DIM];   // 24576 B
    const int t = threadIdx.x;
    float* base = y + (size_t)blockIdx.x * (RPB * DIM);
    for (int i = t; i < RPB * DIM / 4; i += 384)
        ((float4*)ys)[i] = ((const float4*)base)[i];
    __syncthreads();

    float acc[RPB];
    #pragma unroll
    for (int i = 0; i < RPB; ++i) acc[i] = 0.f;
    const float* wp = proj_w + t;                 // thread owns output col t
    const float4* ys4 = (const float4*)ys;
    for (int kk4 = 0; kk4 < DIM / 4; ++kk4) {
        float w0 = wp[(kk4 * 4 + 0) * DIM];
        float w1 = wp[(kk4 * 4 + 1) * DIM];
        float w2 = wp[(kk4 * 4 + 2) * DIM];
        float w3 = wp[(kk4 * 4 + 3) * DIM];
        #pragma unroll
        for (int i = 0; i < RPB; ++i) {
            float4 xv = ys4[i * 96 + kk4];        // broadcast within wave
            acc[i] += xv.x * w0 + xv.y * w1 + xv.z * w2 + xv.w * w3;
        }
    }
    float bv = proj_b[t];
    #pragma unroll
    for (int i = 0; i < RPB; ++i)
        base[i * DIM + t] = acc[i] + bv;
}

extern "C" void kernel_launch(void* const* d_in, const int* in_sizes, int n_in,
                              void* d_out, int out_size, void* d_ws, size_t ws_size,
                              hipStream_t stream) {
    const float* x      = (const float*)d_in[0];
    const float* mask   = (const float*)d_in[1];
    const float* qkv_w  = (const float*)d_in[2];
    const float* qkv_b  = (const float*)d_in[3];
    const float* proj_w = (const float*)d_in[4];
    const float* proj_b = (const float*)d_in[5];
    const float* rpb    = (const float*)d_in[6];
    const int*   rel    = (const int*)d_in[7];
    float* out = (float*)d_out;

    win_attn_kernel<<<NWIN, THREADS_A, 0, stream>>>(x, mask, qkv_w, qkv_b, rpb, rel, out);
    proj_kernel<<<(NWIN * NT) / RPB, 384, 0, stream>>>(proj_w, proj_b, out);
}